// Round 7
// baseline (261.337 us; speedup 1.0000x reference)
//
#include <hip/hip_runtime.h>
#include <cstdint>
#include <cstddef>
#include <type_traits>

// ---------------------------------------------------------------------------
// FlashSparseAttention: X->QKV proj -> RoPE -> causal GQA flash attn -> O proj
// B=2 S=2048 H=2048 NH=16 NKV=4 HD=128, fp32 in/out, bf16 MFMA internally.
// R7: attn Q-tile 256 (32 rows/wave, two fragment sets sharing every K/V
//     ds_read and all staging/barrier overhead), unpaired q-tile blocks
//     (grid 256, NIT=4qt+4), 3-slot ring kept.
// ---------------------------------------------------------------------------

typedef __bf16 bf16x8 __attribute__((ext_vector_type(8)));
typedef float f32x4 __attribute__((ext_vector_type(4)));

#define DEVFN static __device__ __forceinline__

constexpr int Bc = 2, Sc = 2048, Hc = 2048, NHc = 16, NKVc = 4, HDc = 128;
constexpr float SM_SCALE = 0.08838834764831845f;   // 1/sqrt(128)
constexpr float QSCALE = 0.127517431f;             // SM_SCALE * log2(e)
constexpr float DEFER_THR = 11.0f;                 // ~8 nats in log2 domain

DEVFN unsigned short f2bf(float f) {
  __bf16 h = (__bf16)f;                            // native v_cvt RNE
  return __builtin_bit_cast(unsigned short, h);
}
DEVFN float bf2f(unsigned short s) { return __uint_as_float(((unsigned)s) << 16); }

DEVFN void gload_lds16(const void* g, void* l) {
  __builtin_amdgcn_global_load_lds(
      (const __attribute__((address_space(1))) unsigned int*)g,
      (__attribute__((address_space(3))) unsigned int*)l, 16, 0, 0);
}

// ---------------- fp32 -> bf16 conversion (vectorized x4) ------------------
__global__ __launch_bounds__(256) void cvt_kernel(const float* __restrict__ in,
                                                  unsigned short* __restrict__ out,
                                                  int n4) {
  int i = blockIdx.x * 256 + threadIdx.x;
  if (i >= n4) return;
  float4 v = reinterpret_cast<const float4*>(in)[i];
  ushort4 o;
  o.x = f2bf(v.x); o.y = f2bf(v.y); o.z = f2bf(v.z); o.w = f2bf(v.w);
  reinterpret_cast<ushort4*>(out)[i] = o;
}

// ---------------- fused weight conversion (Wq|Wk|Wv -> Wqkv, Wo -> Wob) ----
__global__ __launch_bounds__(256) void cvt_weights(const float* __restrict__ Wq,
                                                   const float* __restrict__ Wk,
                                                   const float* __restrict__ Wv,
                                                   const float* __restrict__ Wo,
                                                   unsigned short* __restrict__ Wqkv,
                                                   unsigned short* __restrict__ Wob) {
  const int i = blockIdx.x * 256 + threadIdx.x;  // float4 index, total 2621440
  const float* src;
  unsigned short* dst;
  int off;
  if (i < 1048576) { src = Wq; dst = Wqkv; off = i; }
  else if (i < 1310720) { src = Wk; dst = Wqkv + 4194304; off = i - 1048576; }
  else if (i < 1572864) { src = Wv; dst = Wqkv + 5242880; off = i - 1310720; }
  else { src = Wo; dst = Wob; off = i - 1572864; }
  float4 v = reinterpret_cast<const float4*>(src)[off];
  ushort4 o;
  o.x = f2bf(v.x); o.y = f2bf(v.y); o.z = f2bf(v.z); o.w = f2bf(v.w);
  reinterpret_cast<ushort4*>(dst)[off] = o;
}

// ---------------- RoPE cos/sin table: [s][d] d in 0..63, f32 ---------------
__global__ __launch_bounds__(256) void rope_table(float* __restrict__ cosT,
                                                  float* __restrict__ sinT) {
  const int i = blockIdx.x * 256 + threadIdx.x;  // 131072 = 2048*64
  const int s = i >> 6, d = i & 63;
  const float inv = exp2f(-0.2076205059304601f * (float)d);  // 10000^(-d/64)
  float sn, c;
  sincosf((float)s * inv, &sn, &c);
  cosT[i] = c;
  sinT[i] = sn;
}

// ---------------- ring-pipelined NT GEMM (bf16 MFMA, K=2048) ----------------
template <int MREP, int MODE>
__global__ __launch_bounds__(512, 2) void gemm_ring(const unsigned short* __restrict__ A,
                                                    const unsigned short* __restrict__ Bw,
                                                    void* __restrict__ o0,
                                                    void* __restrict__ o1,
                                                    void* __restrict__ o2) {
  constexpr int ACH = MREP / 4;
  constexpr int NCH = ACH + 2;
  constexpr int ABY = ACH * 8192;
  constexpr int SLOT = ABY + 16384;
  constexpr int T = 64;
  __shared__ __align__(16) char smem[3 * SLOT];

  const int tid = threadIdx.x;
  const int w = tid >> 6, l = tid & 63;
  const int g = l >> 4, lc = l & 15;
  const int wm = w >> 2, wn = w & 3;

  const int bid = blockIdx.x;
  int bm, bn;
  if (MODE == 2) {
    const int wgid = (bid & 7) * 24 + (bid >> 3);
    bm = (wgid & 15) << 8;
    bn = (wgid >> 4) << 8;
  } else {
    const int wgid = (bid & 7) * 32 + (bid >> 3);
    bm = (wgid & 31) << 7;
    bn = (wgid >> 5) << 8;
  }

  const int u = (tid & 7) ^ ((tid >> 3) & 7);
  const int sr = ((tid >> 3) << 1) + (u >> 2);
  const int scb = (u & 3) << 4;
  const char* Agp = (const char*)A + ((size_t)(bm + sr) << 12) + scb;
  const char* Bgp = (const char*)Bw + ((size_t)(bn + sr) << 12) + scb;
  char* ldst = smem + tid * 16;

  auto stage = [&](int slot, int kt) {
    const int kb = kt * 64;
#pragma unroll
    for (int c = 0; c < ACH; c++)
      gload_lds16(Agp + ((size_t)c << 19) + kb, ldst + slot + c * 8192);
#pragma unroll
    for (int c = 0; c < 2; c++)
      gload_lds16(Bgp + ((size_t)c << 19) + kb, ldst + slot + ABY + c * 8192);
  };

  const int CH = (((lc & 1) << 2) + g) ^ (lc >> 1);
  const int laneA = (wm * (MREP * 8) + (lc >> 1)) * 128 + CH * 16;
  const int laneB = ABY + (wn * 32 + (lc >> 1)) * 128 + CH * 16;

  f32x4 zero4 = {0.f, 0.f, 0.f, 0.f};
  f32x4 acc[MREP][4];
#pragma unroll
  for (int i = 0; i < MREP; i++)
#pragma unroll
    for (int j = 0; j < 4; j++) acc[i][j] = zero4;

  int r0 = 0, r1 = SLOT, r2 = 2 * SLOT;
  stage(r0, 0);
  stage(r1, 1);

  for (int j = 0; j < T; ++j) {
    if (j < T - 1) {
      asm volatile("s_waitcnt vmcnt(%0)" ::"n"(NCH) : "memory");
    } else {
      asm volatile("s_waitcnt vmcnt(0)" ::: "memory");
    }
    asm volatile("s_barrier" ::: "memory");
    if (j + 2 < T) stage(r2, j + 2);

    const char* pa = smem + r0 + laneA;
    const char* pb = smem + r0 + laneB;
    bf16x8 af[MREP], bfr[4];
#pragma unroll
    for (int mi = 0; mi < MREP; mi++) af[mi] = *(const bf16x8*)(pa + mi * 1024);
#pragma unroll
    for (int nj = 0; nj < 4; nj++) bfr[nj] = *(const bf16x8*)(pb + nj * 1024);

    __builtin_amdgcn_s_setprio(1);
#pragma unroll
    for (int mi = 0; mi < MREP; mi++)
#pragma unroll
      for (int nj = 0; nj < 4; nj++)
        acc[mi][nj] = __builtin_amdgcn_mfma_f32_16x16x32_bf16(af[mi], bfr[nj], acc[mi][nj], 0, 0, 0);
    __builtin_amdgcn_s_setprio(0);

    const int t = r0; r0 = r1; r1 = r2; r2 = t;
  }

#pragma unroll
  for (int mi = 0; mi < MREP; mi++) {
#pragma unroll
    for (int nj = 0; nj < 4; nj++) {
#pragma unroll
      for (int r = 0; r < 4; r++) {
        const int row = bm + wm * (MREP * 16) + mi * 16 + (g << 2) + r;
        const int col = bn + wn * 64 + nj * 16 + lc;
        const float v = acc[mi][nj][r];
        if (MODE == 1) {
          ((float*)o0)[(size_t)row * 2048 + col] = v;
        } else {
          const unsigned short q = f2bf(v);
          if (bn < 2048) {
            ((unsigned short*)o0)[(size_t)row * 2048 + col] = q;
          } else if (bn < 2560) {
            ((unsigned short*)o1)[(size_t)row * 512 + (col - 2048)] = q;
          } else {
            const int cv = col - 2560;
            ((unsigned short*)o2)[((size_t)(((row >> 11) * NKVc + (cv >> 7)) * HDc + (cv & 127)) << 11) +
                                  (row & 2047)] = q;
          }
        }
      }
    }
  }
}

// ---------------- K RoPE + relayout: raw[tok][kv*128+d] -> [b][kv][s][d] ----
__global__ __launch_bounds__(256) void rope_k(const unsigned short* __restrict__ raw,
                                              unsigned short* __restrict__ dst,
                                              const float* __restrict__ cosT,
                                              const float* __restrict__ sinT) {
  const int t = blockIdx.x * 256 + threadIdx.x;
  const int d = t & 63;
  const int h = (t >> 6) & 3;
  const int tok = t >> 8;
  const int b = tok >> 11, s = tok & 2047;
  const float c = cosT[(s << 6) + d];
  const float sn = sinT[(s << 6) + d];
  const size_t src = (size_t)tok * 512 + h * 128 + d;
  const float x0 = bf2f(raw[src]);
  const float x1 = bf2f(raw[src + 64]);
  const size_t db = ((size_t)(b * NKVc + h) * Sc + s) * HDc + d;
  dst[db] = f2bf(x0 * c - x1 * sn);
  dst[db + 64] = f2bf(x1 * c + x0 * sn);
}

// ---------------- causal GQA flash attention (R7: Q-tile 256, 2 sets) -------
// grid 256 = 8 q-tiles x 32 bh; 8 waves; 32 q-rows/wave (2 fragment sets of
// 16 rows); KV-tile 64; NIT = 4*qt+4 iterations. LDS: 3 ring slots of 32KB
// (K 16KB + V 16KB) @0/32768/65536; P per-wave 2x2KB @98304+w*4096.
// Every K/V ds_read feeds two MFMAs (one per set) - staging, barriers,
// vmcnt waits and LDS traffic amortized over 2x the output rows.
__global__ __launch_bounds__(512, 2) void attn_kernel(const unsigned short* __restrict__ Qraw,
                                                      const unsigned short* __restrict__ Kr,
                                                      const unsigned short* __restrict__ Vt,
                                                      unsigned short* __restrict__ O,
                                                      const float* __restrict__ cosT,
                                                      const float* __restrict__ sinT) {
  __shared__ __align__(16) char smem[131072];

  const int tid = threadIdx.x, w = tid >> 6, l = tid & 63;
  const int g = l >> 4, lc = l & 15;
  const int bh = blockIdx.x & 31, qt = blockIdx.x >> 5;
  const int b = bh >> 4, h = bh & 15, kvh = h >> 2;
  const int NIT = 4 * qt + 4;

  const char* Kb = (const char*)(Kr + (size_t)(b * NKVc + kvh) * Sc * HDc);
  const char* Vb = (const char*)(Vt + (size_t)(b * NKVc + kvh) * HDc * Sc);

  // staging lane constants (512 threads; pre-swizzled global source)
  const int ksr = tid >> 4;                              // K: 32 rows x 256B / issue
  const int kcb = ((tid & 15) * 16) ^ ((ksr & 7) << 4);
  const int vsr = tid >> 3;                              // V: 64 rows x 128B / issue
  const int vcb = ((tid & 7) * 16) ^ ((vsr & 7) << 4);
  char* ldst = smem + tid * 16;

  auto stage = [&](int slot, int kt_) {
    gload_lds16(Kb + (size_t)(kt_ * 64 + ksr) * 256 + kcb, ldst + slot);
    gload_lds16(Kb + (size_t)(kt_ * 64 + 32 + ksr) * 256 + kcb, ldst + slot + 8192);
    gload_lds16(Vb + (size_t)vsr * 4096 + kt_ * 128 + vcb, ldst + slot + 16384);
    gload_lds16(Vb + (size_t)(64 + vsr) * 4096 + kt_ * 128 + vcb, ldst + slot + 24576);
  };

  // swizzled read bases (slot-relative byte offsets)
  const int swb = ((g ^ lc) & 3) * 16 + ((lc >> 2) & 1) * 64;
  const int kbA = lc * 256 + swb;        // + slot + nf*4096 + (kk>>1)*128 (^64 kk odd)
  const int vbA = lc * 128 + swb;        // + slot+16384 + df*2048 (^64 k2 odd)
  const int pwb = 98304 + w * 4096;      // set0 @ +0, set1 @ +2048
  int pwo[8];
#pragma unroll
  for (int r = 0; r < 4; r++)
#pragma unroll
    for (int n1 = 0; n1 < 2; n1++)
      pwo[r * 2 + n1] = pwb + (g * 4 + r) * 128 + (lc & 7) * 2 +
                        16 * (((lc >> 3) & 1) ^ (r & 1)) + 64 * (n1 ^ (g & 1));

  bf16x8 qf0[4], qf1[4];
  auto loadQ = [&](int srow, bf16x8 (&qf)[4]) {
    const unsigned short* Qb = Qraw + ((size_t)(b * Sc + srow) << 11) + h * 128 + (g << 3);
    float x[4][8];
#pragma unroll
    for (int kk = 0; kk < 4; kk++) {
      const bf16x8 v = *reinterpret_cast<const bf16x8*>(Qb + kk * 32);
#pragma unroll
      for (int j = 0; j < 8; j++) x[kk][j] = (float)v[j] * QSCALE;
    }
#pragma unroll
    for (int kk = 0; kk < 2; kk++) {
      const float* cp = cosT + ((size_t)srow << 6) + kk * 32 + (g << 3);
      const float* sp = sinT + ((size_t)srow << 6) + kk * 32 + (g << 3);
      const float4 c0 = *(const float4*)cp, c1 = *(const float4*)(cp + 4);
      const float4 s0 = *(const float4*)sp, s1 = *(const float4*)(sp + 4);
      const float cs[8] = {c0.x, c0.y, c0.z, c0.w, c1.x, c1.y, c1.z, c1.w};
      const float ss[8] = {s0.x, s0.y, s0.z, s0.w, s1.x, s1.y, s1.z, s1.w};
#pragma unroll
      for (int j = 0; j < 8; j++) {
        qf[kk][j] = (__bf16)(x[kk][j] * cs[j] - x[kk + 2][j] * ss[j]);
        qf[kk + 2][j] = (__bf16)(x[kk + 2][j] * cs[j] + x[kk][j] * ss[j]);
      }
    }
  };

  f32x4 zero4 = {0.f, 0.f, 0.f, 0.f};
  f32x4 oacc0[8], oacc1[8];
#pragma unroll
  for (int i = 0; i < 8; i++) { oacc0[i] = zero4; oacc1[i] = zero4; }
  float mreg[2][4], sume[2][4];
#pragma unroll
  for (int s = 0; s < 2; s++)
#pragma unroll
    for (int r = 0; r < 4; r++) { mreg[s][r] = -1e30f; sume[s][r] = 0.f; }

  loadQ(qt * 256 + w * 16 + lc, qf0);
  loadQ(qt * 256 + 128 + w * 16 + lc, qf1);
  stage(0, 0);
  stage(32768, 1);

  auto iter = [&](int i, auto slotc) {
    constexpr int SB = decltype(slotc)::value;       // slot of tile i
    constexpr int SB2 = (SB + 65536) % 98304;        // slot of tile i+2
    const int kt = i;
    if (i < NIT - 2) {
      asm volatile("s_waitcnt vmcnt(4)" ::: "memory");
    } else {
      asm volatile("s_waitcnt vmcnt(0)" ::: "memory");
    }
    __builtin_amdgcn_s_barrier();
    if (i + 2 < NIT) stage(SB2, i + 2);

    // S = Q K^T for both row-sets, sharing every kf ds_read
    f32x4 sacc0[4], sacc1[4];
#pragma unroll
    for (int nf = 0; nf < 4; nf++) { sacc0[nf] = zero4; sacc1[nf] = zero4; }
    __builtin_amdgcn_s_setprio(1);
#pragma unroll
    for (int nf = 0; nf < 4; nf++) {
#pragma unroll
      for (int kk = 0; kk < 4; kk++) {
        const bf16x8 kf = *reinterpret_cast<const bf16x8*>(
            smem + SB + ((kk & 1) ? (kbA ^ 64) : kbA) + nf * 4096 + (kk >> 1) * 128);
        sacc0[nf] = __builtin_amdgcn_mfma_f32_16x16x32_bf16(qf0[kk], kf, sacc0[nf], 0, 0, 0);
        sacc1[nf] = __builtin_amdgcn_mfma_f32_16x16x32_bf16(qf1[kk], kf, sacc1[nf], 0, 0, 0);
      }
    }
    __builtin_amdgcn_s_setprio(0);

    // causal mask (set s active when kt >= 4*qt + 2*s)
#pragma unroll
    for (int s = 0; s < 2; s++) {
      if (kt >= 4 * qt + 2 * s) {
        const int qrow = qt * 256 + s * 128 + (w << 4) + (g << 2) - (kt << 6);
        f32x4* sa = s ? sacc1 : sacc0;
#pragma unroll
        for (int nf = 0; nf < 4; nf++) {
          const int kvl = nf * 16 + lc;
#pragma unroll
          for (int r = 0; r < 4; r++)
            if (kvl > qrow + r) sa[nf][r] = -1e30f;
        }
      }
    }

    // online softmax with defer-max (both sets)
    float tmax[2][4];
#pragma unroll
    for (int s = 0; s < 2; s++) {
      const f32x4* sa = s ? sacc1 : sacc0;
#pragma unroll
      for (int r = 0; r < 4; r++) {
        float t = fmaxf(fmaxf(sa[0][r], sa[1][r]), fmaxf(sa[2][r], sa[3][r]));
#pragma unroll
        for (int m = 1; m < 16; m <<= 1) t = fmaxf(t, __shfl_xor(t, m));
        tmax[s][r] = t;
      }
    }
    bool ok = true;
#pragma unroll
    for (int s = 0; s < 2; s++)
#pragma unroll
      for (int r = 0; r < 4; r++) ok = ok && (tmax[s][r] <= mreg[s][r] + DEFER_THR);
    if (!__all(ok)) {
#pragma unroll
      for (int s = 0; s < 2; s++) {
        float alpha[4];
#pragma unroll
        for (int r = 0; r < 4; r++) {
          const float mn = fmaxf(mreg[s][r], tmax[s][r]);
          alpha[r] = exp2f(mreg[s][r] - mn);
          mreg[s][r] = mn;
          sume[s][r] *= alpha[r];
        }
        f32x4* oa = s ? oacc1 : oacc0;
#pragma unroll
        for (int i2 = 0; i2 < 8; i2++) {
          f32x4 t = oa[i2];
          t[0] *= alpha[0]; t[1] *= alpha[1]; t[2] *= alpha[2]; t[3] *= alpha[3];
          oa[i2] = t;
        }
      }
    }

    // P = exp2(S - m) -> per-wave LDS (imm-offset swizzled), both sets
#pragma unroll
    for (int s = 0; s < 2; s++) {
      const f32x4* sa = s ? sacc1 : sacc0;
#pragma unroll
      for (int nf = 0; nf < 4; nf++) {
#pragma unroll
        for (int r = 0; r < 4; r++) {
          const float pv = exp2f(sa[nf][r] - mreg[s][r]);
          sume[s][r] += pv;
          *(unsigned short*)(smem + pwo[r * 2 + (nf >> 1)] + s * 2048 +
                             32 * ((nf & 1) ^ ((r >> 1) & 1))) = f2bf(pv);
        }
      }
    }

    // O += P V : every vf ds_read feeds both sets
    __builtin_amdgcn_s_setprio(1);
#pragma unroll
    for (int k2 = 0; k2 < 2; k2++) {
      const int sb = k2 ? (vbA ^ 64) : vbA;
      const bf16x8 pf0 = *reinterpret_cast<const bf16x8*>(smem + pwb + sb);
      const bf16x8 pf1 = *reinterpret_cast<const bf16x8*>(smem + pwb + 2048 + sb);
#pragma unroll
      for (int df = 0; df < 8; df++) {
        const bf16x8 vf =
            *reinterpret_cast<const bf16x8*>(smem + SB + 16384 + sb + df * 2048);
        oacc0[df] = __builtin_amdgcn_mfma_f32_16x16x32_bf16(pf0, vf, oacc0[df], 0, 0, 0);
        oacc1[df] = __builtin_amdgcn_mfma_f32_16x16x32_bf16(pf1, vf, oacc1[df], 0, 0, 0);
      }
    }
    __builtin_amdgcn_s_setprio(0);

    asm volatile("s_waitcnt lgkmcnt(0)" ::: "memory");   // drain before next barrier
  };

  int i = 0;
  const int ntrip = NIT / 3;
  for (int t3 = 0; t3 < ntrip; ++t3) {
    iter(i, std::integral_constant<int, 0>{}); i++;
    iter(i, std::integral_constant<int, 32768>{}); i++;
    iter(i, std::integral_constant<int, 65536>{}); i++;
  }
  if (i < NIT) { iter(i, std::integral_constant<int, 0>{}); i++; }
  if (i < NIT) { iter(i, std::integral_constant<int, 32768>{}); i++; }

  // epilogue: normalize and write both sets
#pragma unroll
  for (int s = 0; s < 2; s++) {
    float rinv[4];
#pragma unroll
    for (int r = 0; r < 4; r++) {
      float t = sume[s][r];
#pragma unroll
      for (int m = 1; m < 16; m <<= 1) t += __shfl_xor(t, m);
      rinv[r] = 1.0f / t;
    }
    const f32x4* oa = s ? oacc1 : oacc0;
    unsigned short* Ob = O +
        ((size_t)(b * Sc + qt * 256 + s * 128 + (w << 4) + (g << 2)) * (NHc * HDc)) +
        h * HDc + lc;
#pragma unroll
    for (int df = 0; df < 8; df++)
#pragma unroll
      for (int r = 0; r < 4; r++)
        Ob[(size_t)r * (NHc * HDc) + df * 16] = f2bf(oa[df][r] * rinv[r]);
  }
}

// ---------------------------------------------------------------------------
extern "C" void kernel_launch(void* const* d_in, const int* in_sizes, int n_in,
                              void* d_out, int out_size, void* d_ws, size_t ws_size,
                              hipStream_t stream) {
  (void)in_sizes; (void)n_in; (void)out_size; (void)ws_size;
  const float* X = (const float*)d_in[0];
  const float* Wq = (const float*)d_in[1];
  const float* Wk = (const float*)d_in[2];
  const float* Wv = (const float*)d_in[3];
  const float* Wo = (const float*)d_in[4];

  char* ws = (char*)d_ws;
  unsigned short* Xbf  = (unsigned short*)(ws + 0);         // 4096x2048 (16MB)
  unsigned short* Wqkv = (unsigned short*)(ws + 16777216);  // 3072x2048 (12.6MB)
  unsigned short* Wob  = (unsigned short*)(ws + 29360128);  // 2048x2048 (8MB)
  unsigned short* Qraw = (unsigned short*)(ws + 37748736);  // 4096x2048 (16MB)
  unsigned short* Kraw = (unsigned short*)(ws + 54525952);  // 4096x512  (4MB)
  unsigned short* Vt   = (unsigned short*)(ws + 58720256);  // [b][kv][d][s] (4MB)
  float*          cosT = (float*)(ws + 62914560);           // 2048x64 f32 (512KB)
  float*          sinT = (float*)(ws + 63438848);           // 2048x64 f32 (512KB)
  unsigned short* Kr   = (unsigned short*)(ws + 79691776);  // [b][kv][s][d] (4MB)
  unsigned short* Ows  = (unsigned short*)(ws + 83886080);  // 4096x2048 (16MB)

  rope_table<<<512, 256, 0, stream>>>(cosT, sinT);
  cvt_kernel<<<8192, 256, 0, stream>>>(X, Xbf, 2097152);
  cvt_weights<<<10240, 256, 0, stream>>>(Wq, Wk, Wv, Wo, Wqkv, Wob);

  gemm_ring<8, 2><<<192, 512, 0, stream>>>(Xbf, Wqkv, Qraw, Kraw, Vt);

  rope_k<<<4096, 256, 0, stream>>>(Kraw, Kr, cosT, sinT);

  attn_kernel<<<256, 512, 0, stream>>>(Qraw, Kr, Vt, Ows, cosT, sinT);

  gemm_ring<4, 1><<<256, 512, 0, stream>>>(Ows, Wob, d_out, nullptr, nullptr);
}

// Round 8
// 213.820 us; speedup vs baseline: 1.2222x; 1.2222x over previous
//
#include <hip/hip_runtime.h>
#include <cstdint>
#include <cstddef>
#include <type_traits>

// ---------------------------------------------------------------------------
// FlashSparseAttention: X->QKV proj -> RoPE -> causal GQA flash attn -> O proj
// B=2 S=2048 H=2048 NH=16 NKV=4 HD=128, fp32 in/out, bf16 MFMA internally.
// R8: attn rewritten to the m214-style structure: 4 waves = 4 GQA heads/block
//     sharing K/V staging; 32x32x16 MFMA with swapped QK^T (S^T in regs);
//     in-register softmax (fmax tree + shfl_xor(32)); P->PV via
//     cvt_pk_bf16 + permlane32_swap (no P LDS roundtrip); 32-row q-tiles
//     paired (63-p, p) -> exactly 33 KV iterations per block (perfect balance);
//     grid 256 = 32 pairs x 8 kv-groups, 64KB LDS dbuf -> 2 blocks/CU.
// ---------------------------------------------------------------------------

typedef __bf16 bf16x8 __attribute__((ext_vector_type(8)));
typedef float f32x4 __attribute__((ext_vector_type(4)));
typedef float f32x16 __attribute__((ext_vector_type(16)));
typedef int i32x4 __attribute__((ext_vector_type(4)));

#define DEVFN static __device__ __forceinline__

constexpr int Bc = 2, Sc = 2048, Hc = 2048, NHc = 16, NKVc = 4, HDc = 128;
constexpr float SM_SCALE = 0.08838834764831845f;   // 1/sqrt(128)
constexpr float QSCALE = 0.127517431f;             // SM_SCALE * log2(e)
constexpr float DEFER_THR = 11.0f;                 // ~8 nats in log2 domain

DEVFN unsigned short f2bf(float f) {
  __bf16 h = (__bf16)f;
  return __builtin_bit_cast(unsigned short, h);
}
DEVFN float bf2f(unsigned short s) { return __uint_as_float(((unsigned)s) << 16); }

DEVFN unsigned cvtpk(float lo, float hi) {
  unsigned r;
  asm("v_cvt_pk_bf16_f32 %0, %1, %2" : "=v"(r) : "v"(lo), "v"(hi));
  return r;
}
DEVFN void pswap(unsigned& x, unsigned& y) {
  asm("v_permlane32_swap_b32 %0, %1" : "+v"(x), "+v"(y));
}

DEVFN f32x16 mfma32(bf16x8 a, bf16x8 b, f32x16 c) {
  return __builtin_amdgcn_mfma_f32_32x32x16_bf16(a, b, c, 0, 0, 0);
}

DEVFN void gload_lds16(const void* g, void* l) {
  __builtin_amdgcn_global_load_lds(
      (const __attribute__((address_space(1))) unsigned int*)g,
      (__attribute__((address_space(3))) unsigned int*)l, 16, 0, 0);
}

// ---------------- fp32 -> bf16 conversion (vectorized x4) ------------------
__global__ __launch_bounds__(256) void cvt_kernel(const float* __restrict__ in,
                                                  unsigned short* __restrict__ out,
                                                  int n4) {
  int i = blockIdx.x * 256 + threadIdx.x;
  if (i >= n4) return;
  float4 v = reinterpret_cast<const float4*>(in)[i];
  ushort4 o;
  o.x = f2bf(v.x); o.y = f2bf(v.y); o.z = f2bf(v.z); o.w = f2bf(v.w);
  reinterpret_cast<ushort4*>(out)[i] = o;
}

// ---------------- fused weight conversion (Wq|Wk|Wv -> Wqkv, Wo -> Wob) ----
__global__ __launch_bounds__(256) void cvt_weights(const float* __restrict__ Wq,
                                                   const float* __restrict__ Wk,
                                                   const float* __restrict__ Wv,
                                                   const float* __restrict__ Wo,
                                                   unsigned short* __restrict__ Wqkv,
                                                   unsigned short* __restrict__ Wob) {
  const int i = blockIdx.x * 256 + threadIdx.x;  // float4 index, total 2621440
  const float* src;
  unsigned short* dst;
  int off;
  if (i < 1048576) { src = Wq; dst = Wqkv; off = i; }
  else if (i < 1310720) { src = Wk; dst = Wqkv + 4194304; off = i - 1048576; }
  else if (i < 1572864) { src = Wv; dst = Wqkv + 5242880; off = i - 1310720; }
  else { src = Wo; dst = Wob; off = i - 1572864; }
  float4 v = reinterpret_cast<const float4*>(src)[off];
  ushort4 o;
  o.x = f2bf(v.x); o.y = f2bf(v.y); o.z = f2bf(v.z); o.w = f2bf(v.w);
  reinterpret_cast<ushort4*>(dst)[off] = o;
}

// ---------------- RoPE cos/sin table: [s][d] d in 0..63, f32 ---------------
__global__ __launch_bounds__(256) void rope_table(float* __restrict__ cosT,
                                                  float* __restrict__ sinT) {
  const int i = blockIdx.x * 256 + threadIdx.x;  // 131072 = 2048*64
  const int s = i >> 6, d = i & 63;
  const float inv = exp2f(-0.2076205059304601f * (float)d);  // 10000^(-d/64)
  float sn, c;
  sincosf((float)s * inv, &sn, &c);
  cosT[i] = c;
  sinT[i] = sn;
}

// ---------------- ring-pipelined NT GEMM (bf16 MFMA, K=2048) ----------------
template <int MREP, int MODE>
__global__ __launch_bounds__(512, 2) void gemm_ring(const unsigned short* __restrict__ A,
                                                    const unsigned short* __restrict__ Bw,
                                                    void* __restrict__ o0,
                                                    void* __restrict__ o1,
                                                    void* __restrict__ o2) {
  constexpr int ACH = MREP / 4;
  constexpr int NCH = ACH + 2;
  constexpr int ABY = ACH * 8192;
  constexpr int SLOT = ABY + 16384;
  constexpr int T = 64;
  __shared__ __align__(16) char smem[3 * SLOT];

  const int tid = threadIdx.x;
  const int w = tid >> 6, l = tid & 63;
  const int g = l >> 4, lc = l & 15;
  const int wm = w >> 2, wn = w & 3;

  const int bid = blockIdx.x;
  int bm, bn;
  if (MODE == 2) {
    const int wgid = (bid & 7) * 24 + (bid >> 3);
    bm = (wgid & 15) << 8;
    bn = (wgid >> 4) << 8;
  } else {
    const int wgid = (bid & 7) * 32 + (bid >> 3);
    bm = (wgid & 31) << 7;
    bn = (wgid >> 5) << 8;
  }

  const int u = (tid & 7) ^ ((tid >> 3) & 7);
  const int sr = ((tid >> 3) << 1) + (u >> 2);
  const int scb = (u & 3) << 4;
  const char* Agp = (const char*)A + ((size_t)(bm + sr) << 12) + scb;
  const char* Bgp = (const char*)Bw + ((size_t)(bn + sr) << 12) + scb;
  char* ldst = smem + tid * 16;

  auto stage = [&](int slot, int kt) {
    const int kb = kt * 64;
#pragma unroll
    for (int c = 0; c < ACH; c++)
      gload_lds16(Agp + ((size_t)c << 19) + kb, ldst + slot + c * 8192);
#pragma unroll
    for (int c = 0; c < 2; c++)
      gload_lds16(Bgp + ((size_t)c << 19) + kb, ldst + slot + ABY + c * 8192);
  };

  const int CH = (((lc & 1) << 2) + g) ^ (lc >> 1);
  const int laneA = (wm * (MREP * 8) + (lc >> 1)) * 128 + CH * 16;
  const int laneB = ABY + (wn * 32 + (lc >> 1)) * 128 + CH * 16;

  f32x4 zero4 = {0.f, 0.f, 0.f, 0.f};
  f32x4 acc[MREP][4];
#pragma unroll
  for (int i = 0; i < MREP; i++)
#pragma unroll
    for (int j = 0; j < 4; j++) acc[i][j] = zero4;

  int r0 = 0, r1 = SLOT, r2 = 2 * SLOT;
  stage(r0, 0);
  stage(r1, 1);

  for (int j = 0; j < T; ++j) {
    if (j < T - 1) {
      asm volatile("s_waitcnt vmcnt(%0)" ::"n"(NCH) : "memory");
    } else {
      asm volatile("s_waitcnt vmcnt(0)" ::: "memory");
    }
    asm volatile("s_barrier" ::: "memory");
    if (j + 2 < T) stage(r2, j + 2);

    const char* pa = smem + r0 + laneA;
    const char* pb = smem + r0 + laneB;
    bf16x8 af[MREP], bfr[4];
#pragma unroll
    for (int mi = 0; mi < MREP; mi++) af[mi] = *(const bf16x8*)(pa + mi * 1024);
#pragma unroll
    for (int nj = 0; nj < 4; nj++) bfr[nj] = *(const bf16x8*)(pb + nj * 1024);

    __builtin_amdgcn_s_setprio(1);
#pragma unroll
    for (int mi = 0; mi < MREP; mi++)
#pragma unroll
      for (int nj = 0; nj < 4; nj++)
        acc[mi][nj] = __builtin_amdgcn_mfma_f32_16x16x32_bf16(af[mi], bfr[nj], acc[mi][nj], 0, 0, 0);
    __builtin_amdgcn_s_setprio(0);

    const int t = r0; r0 = r1; r1 = r2; r2 = t;
  }

#pragma unroll
  for (int mi = 0; mi < MREP; mi++) {
#pragma unroll
    for (int nj = 0; nj < 4; nj++) {
#pragma unroll
      for (int r = 0; r < 4; r++) {
        const int row = bm + wm * (MREP * 16) + mi * 16 + (g << 2) + r;
        const int col = bn + wn * 64 + nj * 16 + lc;
        const float v = acc[mi][nj][r];
        if (MODE == 1) {
          ((float*)o0)[(size_t)row * 2048 + col] = v;
        } else {
          const unsigned short q = f2bf(v);
          if (bn < 2048) {
            ((unsigned short*)o0)[(size_t)row * 2048 + col] = q;
          } else if (bn < 2560) {
            ((unsigned short*)o1)[(size_t)row * 512 + (col - 2048)] = q;
          } else {
            const int cv = col - 2560;
            ((unsigned short*)o2)[((size_t)(((row >> 11) * NKVc + (cv >> 7)) * HDc + (cv & 127)) << 11) +
                                  (row & 2047)] = q;
          }
        }
      }
    }
  }
}

// ---------------- K RoPE + relayout: raw[tok][kv*128+d] -> [b][kv][s][d] ----
__global__ __launch_bounds__(256) void rope_k(const unsigned short* __restrict__ raw,
                                              unsigned short* __restrict__ dst,
                                              const float* __restrict__ cosT,
                                              const float* __restrict__ sinT) {
  const int t = blockIdx.x * 256 + threadIdx.x;
  const int d = t & 63;
  const int h = (t >> 6) & 3;
  const int tok = t >> 8;
  const int b = tok >> 11, s = tok & 2047;
  const float c = cosT[(s << 6) + d];
  const float sn = sinT[(s << 6) + d];
  const size_t src = (size_t)tok * 512 + h * 128 + d;
  const float x0 = bf2f(raw[src]);
  const float x1 = bf2f(raw[src + 64]);
  const size_t db = ((size_t)(b * NKVc + h) * Sc + s) * HDc + d;
  dst[db] = f2bf(x0 * c - x1 * sn);
  dst[db + 64] = f2bf(x1 * c + x0 * sn);
}

// ---------------- causal GQA flash attention (R8: 32x32, swapped QK^T) ------
// grid 256: bid -> kvb = bid&7 (XCD-local KV), pair p = bid>>3 (0..31).
// Block: 4 waves = 4 q-heads of group kvh; q-tiles t0=63-p then t1=p (32 rows
// each); NIT = (t0>>1)+1 + (t1>>1)+1 = 33 for every block. KV-tile 64.
// LDS: 2 slots of 32KB (K 64x256B swz + V^T 128x128B swz) @0/@32768.
// Per wave: S^T[kv 64][q 32] = mfma32(K_frag, Q_frag); softmax in-register
// (q = lane col, kv in regs; fmax tree + shfl_xor(32)); P^T built in-register
// via cvt_pk_bf16 + permlane32_swap; O^T[d][q] += mfma32(V^T_frag, P^T).
__global__ __launch_bounds__(256, 2) void attn_kernel(const unsigned short* __restrict__ Qraw,
                                                      const unsigned short* __restrict__ Kr,
                                                      const unsigned short* __restrict__ Vt,
                                                      unsigned short* __restrict__ O,
                                                      const float* __restrict__ cosT,
                                                      const float* __restrict__ sinT) {
  __shared__ __align__(16) char smem[65536];

  const int tid = threadIdx.x, w = tid >> 6, l = tid & 63;
  const int lq = l & 31, lh = l >> 5;
  const int kvb = blockIdx.x & 7, p = blockIdx.x >> 3;
  const int b = kvb >> 2, kvh = kvb & 3, h = kvh * 4 + w;
  const int t0 = 63 - p, t1 = p;
  const int NIT0 = (t0 >> 1) + 1;
  const int NIT1 = (t1 >> 1) + 1;   // NIT0 + NIT1 == 33 always

  const char* Kb = (const char*)(Kr + (size_t)(b * NKVc + kvh) * Sc * HDc);
  const char* Vb = (const char*)(Vt + (size_t)(b * NKVc + kvh) * HDc * Sc);

  // staging (256 threads, 16B x 8 per thread per tile; pre-swizzled source)
  const int krow0 = tid >> 4;                             // K: 16 rows x 256B /issue
  const int kcb = ((tid & 15) * 16) ^ ((krow0 & 7) << 4);
  const int vrow0 = tid >> 3;                             // V: 32 rows x 128B /issue
  const int vcb = ((tid & 7) * 16) ^ ((vrow0 & 7) << 4);
  char* ldst = smem + tid * 16;

  auto stage = [&](int slot, int kt_) {
#pragma unroll
    for (int c = 0; c < 4; c++)
      gload_lds16(Kb + (size_t)(kt_ * 64 + krow0 + 16 * c) * 256 + kcb,
                  ldst + slot + c * 4096);
#pragma unroll
    for (int c = 0; c < 4; c++)
      gload_lds16(Vb + (size_t)(vrow0 + 32 * c) * 4096 + kt_ * 128 + vcb,
                  ldst + slot + 16384 + c * 4096);
  };

  // read constants: A-frag row = lane&31, k = lh*8+j (16B); swizzle by row&7
  const int swz = (l & 7) << 4;
  const int hi16 = lh << 4;
  int co[8];
#pragma unroll
  for (int kc = 0; kc < 8; kc++) co[kc] = (kc * 32 + hi16) ^ swz;
  const int kbase = lq * 256;          // + SLOT + kvblk*8192 + co[kc]
  const int vbase = 16384 + lq * 128;  // + SLOT + dblk*4096 + co[kc]

  // Q as B-frags: col=q=lq, k = kc*16 + lh*8 + j; RoPE pairs (kc, kc+4)
  bf16x8 qf[8];
  auto loadQ = [&](int t) {
    const int srow = t * 32 + lq;
    const unsigned short* Qp = Qraw + ((size_t)(b * Sc + srow) << 11) + h * 128 + lh * 8;
#pragma unroll
    for (int kc = 0; kc < 4; kc++) {
      const bf16x8 vlo = *(const bf16x8*)(Qp + kc * 16);
      const bf16x8 vhi = *(const bf16x8*)(Qp + kc * 16 + 64);
      const float* cp = cosT + ((size_t)srow << 6) + kc * 16 + lh * 8;
      const float* sp = sinT + ((size_t)srow << 6) + kc * 16 + lh * 8;
      const float4 c0 = *(const float4*)cp, c1 = *(const float4*)(cp + 4);
      const float4 s0v = *(const float4*)sp, s1v = *(const float4*)(sp + 4);
      const float cs[8] = {c0.x, c0.y, c0.z, c0.w, c1.x, c1.y, c1.z, c1.w};
      const float ss[8] = {s0v.x, s0v.y, s0v.z, s0v.w, s1v.x, s1v.y, s1v.z, s1v.w};
#pragma unroll
      for (int j = 0; j < 8; j++) {
        const float xl = (float)vlo[j] * QSCALE;
        const float xh = (float)vhi[j] * QSCALE;
        qf[kc][j] = (__bf16)(xl * cs[j] - xh * ss[j]);
        qf[kc + 4][j] = (__bf16)(xh * cs[j] + xl * ss[j]);
      }
    }
  };

  f32x16 oacc[4];
#pragma unroll
  for (int d = 0; d < 4; d++)
#pragma unroll
    for (int r = 0; r < 16; r++) oacc[d][r] = 0.f;
  float m_run = -1e30f, sum_run = 0.f;

  int kt = 0, tcur = t0, nlast = NIT0 - 1, phase = 0;
  loadQ(t0);
  stage(0, 0);

  auto iter = [&](int i, auto slotc) {
    constexpr int SLOT = decltype(slotc)::value;
    if (i < 32) {
      const int ni = i + 1;
      stage(SLOT ^ 32768, ni < NIT0 ? ni : ni - NIT0);
      asm volatile("s_waitcnt vmcnt(8)" ::: "memory");
    } else {
      asm volatile("s_waitcnt vmcnt(0)" ::: "memory");
    }
    __builtin_amdgcn_s_barrier();

    // ---- S^T = K Q : two 32x32 blocks (kv 0-31, 32-63) ----
    f32x16 s0, s1;
#pragma unroll
    for (int r = 0; r < 16; r++) { s0[r] = 0.f; s1[r] = 0.f; }
    __builtin_amdgcn_s_setprio(1);
#pragma unroll
    for (int kc = 0; kc < 8; kc++) {
      const bf16x8 kf0 = *(const bf16x8*)(smem + SLOT + kbase + co[kc]);
      const bf16x8 kf1 = *(const bf16x8*)(smem + SLOT + 8192 + kbase + co[kc]);
      s0 = mfma32(kf0, qf[kc], s0);
      s1 = mfma32(kf1, qf[kc], s1);
    }
    __builtin_amdgcn_s_setprio(0);

    // ---- causal mask (diagonal = last iter of each phase) ----
    if (kt == nlast) {
      const int qpos = tcur * 32 + lq;
      const int kv0 = kt * 64 + 4 * lh;
#pragma unroll
      for (int r = 0; r < 16; r++) {
        const int kvv = kv0 + (r & 3) + 8 * (r >> 2);
        if (kvv > qpos) s0[r] = -1e30f;
        if (kvv + 32 > qpos) s1[r] = -1e30f;
      }
    }

    // ---- online softmax: q = lane col; kv in regs + lane^32 ----
    float q8[8];
#pragma unroll
    for (int g4 = 0; g4 < 4; g4++) {
      q8[g4] = fmaxf(fmaxf(s0[4 * g4], s0[4 * g4 + 1]), fmaxf(s0[4 * g4 + 2], s0[4 * g4 + 3]));
      q8[4 + g4] = fmaxf(fmaxf(s1[4 * g4], s1[4 * g4 + 1]), fmaxf(s1[4 * g4 + 2], s1[4 * g4 + 3]));
    }
    float mt = fmaxf(fmaxf(fmaxf(q8[0], q8[1]), fmaxf(q8[2], q8[3])),
                     fmaxf(fmaxf(q8[4], q8[5]), fmaxf(q8[6], q8[7])));
    mt = fmaxf(mt, __shfl_xor(mt, 32));
    if (!__all(mt <= m_run + DEFER_THR)) {
      const float mn = fmaxf(m_run, mt);
      const float al = exp2f(m_run - mn);
      m_run = mn;
      sum_run *= al;
#pragma unroll
      for (int d = 0; d < 4; d++)
#pragma unroll
        for (int r = 0; r < 16; r++) oacc[d][r] *= al;
    }

    float pv0[16], pv1[16];
    float sA = 0.f, sB = 0.f, sC = 0.f, sD = 0.f;
#pragma unroll
    for (int r = 0; r < 16; r += 4) {
      pv0[r] = exp2f(s0[r] - m_run);         sA += pv0[r];
      pv0[r + 1] = exp2f(s0[r + 1] - m_run); sB += pv0[r + 1];
      pv0[r + 2] = exp2f(s0[r + 2] - m_run); sC += pv0[r + 2];
      pv0[r + 3] = exp2f(s0[r + 3] - m_run); sD += pv0[r + 3];
    }
#pragma unroll
    for (int r = 0; r < 16; r += 4) {
      pv1[r] = exp2f(s1[r] - m_run);         sA += pv1[r];
      pv1[r + 1] = exp2f(s1[r + 1] - m_run); sB += pv1[r + 1];
      pv1[r + 2] = exp2f(s1[r + 2] - m_run); sC += pv1[r + 2];
      pv1[r + 3] = exp2f(s1[r + 3] - m_run); sD += pv1[r + 3];
    }
    sum_run += (sA + sB) + (sC + sD);

    // ---- P^T B-frags in-register: cvt_pk + permlane32_swap ----
    bf16x8 pf0, pf1, pf2, pf3;
    {
      unsigned a0 = cvtpk(pv0[0], pv0[1]), a2 = cvtpk(pv0[4], pv0[5]);
      unsigned a1 = cvtpk(pv0[2], pv0[3]), a3 = cvtpk(pv0[6], pv0[7]);
      pswap(a0, a2); pswap(a1, a3);
      i32x4 t4 = {(int)a0, (int)a1, (int)a2, (int)a3};
      pf0 = __builtin_bit_cast(bf16x8, t4);
    }
    {
      unsigned a0 = cvtpk(pv0[8], pv0[9]), a2 = cvtpk(pv0[12], pv0[13]);
      unsigned a1 = cvtpk(pv0[10], pv0[11]), a3 = cvtpk(pv0[14], pv0[15]);
      pswap(a0, a2); pswap(a1, a3);
      i32x4 t4 = {(int)a0, (int)a1, (int)a2, (int)a3};
      pf1 = __builtin_bit_cast(bf16x8, t4);
    }
    {
      unsigned a0 = cvtpk(pv1[0], pv1[1]), a2 = cvtpk(pv1[4], pv1[5]);
      unsigned a1 = cvtpk(pv1[2], pv1[3]), a3 = cvtpk(pv1[6], pv1[7]);
      pswap(a0, a2); pswap(a1, a3);
      i32x4 t4 = {(int)a0, (int)a1, (int)a2, (int)a3};
      pf2 = __builtin_bit_cast(bf16x8, t4);
    }
    {
      unsigned a0 = cvtpk(pv1[8], pv1[9]), a2 = cvtpk(pv1[12], pv1[13]);
      unsigned a1 = cvtpk(pv1[10], pv1[11]), a3 = cvtpk(pv1[14], pv1[15]);
      pswap(a0, a2); pswap(a1, a3);
      i32x4 t4 = {(int)a0, (int)a1, (int)a2, (int)a3};
      pf3 = __builtin_bit_cast(bf16x8, t4);
    }

    // ---- O^T += V^T P^T ----
    __builtin_amdgcn_s_setprio(1);
#pragma unroll
    for (int d = 0; d < 4; d++) {
      oacc[d] = mfma32(*(const bf16x8*)(smem + SLOT + vbase + d * 4096 + co[0]), pf0, oacc[d]);
      oacc[d] = mfma32(*(const bf16x8*)(smem + SLOT + vbase + d * 4096 + co[1]), pf1, oacc[d]);
      oacc[d] = mfma32(*(const bf16x8*)(smem + SLOT + vbase + d * 4096 + co[2]), pf2, oacc[d]);
      oacc[d] = mfma32(*(const bf16x8*)(smem + SLOT + vbase + d * 4096 + co[3]), pf3, oacc[d]);
    }
    __builtin_amdgcn_s_setprio(0);

    asm volatile("s_waitcnt lgkmcnt(0)" ::: "memory");

    if (kt == nlast) {
      // ---- epilogue: normalize, write O^T (lane q = col, d in regs) ----
      const float st = sum_run + __shfl_xor(sum_run, 32);
      const float rinv = 1.0f / st;
      unsigned short* Op = O + ((size_t)(b * Sc + tcur * 32 + lq) << 11) + h * 128 + lh * 4;
#pragma unroll
      for (int d = 0; d < 4; d++) {
#pragma unroll
        for (int rq = 0; rq < 4; rq++) {
          uint2 u2;
          u2.x = cvtpk(oacc[d][4 * rq] * rinv, oacc[d][4 * rq + 1] * rinv);
          u2.y = cvtpk(oacc[d][4 * rq + 2] * rinv, oacc[d][4 * rq + 3] * rinv);
          *(uint2*)(Op + d * 32 + rq * 8) = u2;
        }
      }
      if (phase == 0) {
        phase = 1; tcur = t1; kt = 0; nlast = NIT1 - 1;
#pragma unroll
        for (int d = 0; d < 4; d++)
#pragma unroll
          for (int r = 0; r < 16; r++) oacc[d][r] = 0.f;
        m_run = -1e30f;
        sum_run = 0.f;
        loadQ(t1);
      }
    } else {
      kt++;
    }
  };

  for (int u2i = 0; u2i < 16; ++u2i) {
    iter(2 * u2i, std::integral_constant<int, 0>{});
    iter(2 * u2i + 1, std::integral_constant<int, 32768>{});
  }
  iter(32, std::integral_constant<int, 0>{});
}

// ---------------------------------------------------------------------------
extern "C" void kernel_launch(void* const* d_in, const int* in_sizes, int n_in,
                              void* d_out, int out_size, void* d_ws, size_t ws_size,
                              hipStream_t stream) {
  (void)in_sizes; (void)n_in; (void)out_size; (void)ws_size;
  const float* X = (const float*)d_in[0];
  const float* Wq = (const float*)d_in[1];
  const float* Wk = (const float*)d_in[2];
  const float* Wv = (const float*)d_in[3];
  const float* Wo = (const float*)d_in[4];

  char* ws = (char*)d_ws;
  unsigned short* Xbf  = (unsigned short*)(ws + 0);         // 4096x2048 (16MB)
  unsigned short* Wqkv = (unsigned short*)(ws + 16777216);  // 3072x2048 (12.6MB)
  unsigned short* Wob  = (unsigned short*)(ws + 29360128);  // 2048x2048 (8MB)
  unsigned short* Qraw = (unsigned short*)(ws + 37748736);  // 4096x2048 (16MB)
  unsigned short* Kraw = (unsigned short*)(ws + 54525952);  // 4096x512  (4MB)
  unsigned short* Vt   = (unsigned short*)(ws + 58720256);  // [b][kv][d][s] (4MB)
  float*          cosT = (float*)(ws + 62914560);           // 2048x64 f32 (512KB)
  float*          sinT = (float*)(ws + 63438848);           // 2048x64 f32 (512KB)
  unsigned short* Kr   = (unsigned short*)(ws + 79691776);  // [b][kv][s][d] (4MB)
  unsigned short* Ows  = (unsigned short*)(ws + 83886080);  // 4096x2048 (16MB)

  rope_table<<<512, 256, 0, stream>>>(cosT, sinT);
  cvt_kernel<<<8192, 256, 0, stream>>>(X, Xbf, 2097152);
  cvt_weights<<<10240, 256, 0, stream>>>(Wq, Wk, Wv, Wo, Wqkv, Wob);

  gemm_ring<8, 2><<<192, 512, 0, stream>>>(Xbf, Wqkv, Qraw, Kraw, Vt);

  rope_k<<<4096, 256, 0, stream>>>(Kraw, Kr, cosT, sinT);

  attn_kernel<<<256, 256, 0, stream>>>(Qraw, Kr, Vt, Ows, cosT, sinT);

  gemm_ring<4, 1><<<256, 512, 0, stream>>>(Ows, Wob, d_out, nullptr, nullptr);
}